// Round 2
// baseline (412.673 us; speedup 1.0000x reference)
//
#include <hip/hip_runtime.h>
#include <hip/hip_bf16.h>
#include <math.h>

#define NB 8
#define INCH 512
#define OUTCH 256
#define SP 4096          // 64*64 spatial
#define LAT 512
#define NTAP 9
#define MDIM (NTAP*OUTCH)   // 2304

#define INV_SQRT_LAT 0.044194173824159216f   // 1/sqrt(512)
#define WSCALE 0.014731391274719738f         // 1/sqrt(512*9)

typedef __bf16 bf16x8 __attribute__((ext_vector_type(8)));
typedef float  f32x4  __attribute__((ext_vector_type(4)));

__device__ __forceinline__ unsigned short f2bf(float f) {
  unsigned u = __float_as_uint(f);
  u += 0x7fffu + ((u >> 16) & 1u);       // round-to-nearest-even
  return (unsigned short)(u >> 16);
}
__device__ __forceinline__ float bf2f(unsigned short v) {
  return __uint_as_float((unsigned)v << 16);
}

// ---------------- stage 0a+0b fused: style GEMV (blocks 0..15) + weight prep (blocks 16..527)
__global__ void prep_k(const float* __restrict__ w, const float* __restrict__ aff,
                       const float* __restrict__ bias, float* __restrict__ style,
                       const float* __restrict__ cw, float* __restrict__ S,
                       unsigned short* __restrict__ w9) {
  if (blockIdx.x < 16) {
    int gid = blockIdx.x * 256 + threadIdx.x;       // 4096
    int b = gid >> 9, i = gid & 511;
    const float4* wv = (const float4*)(w + (size_t)b * LAT);
    const float4* av = (const float4*)(aff + (size_t)i * LAT);
    float s = 0.f;
#pragma unroll 4
    for (int l = 0; l < LAT / 4; ++l) {
      float4 a = av[l], ww = wv[l];
      s += a.x * ww.x + a.y * ww.y + a.z * ww.z + a.w * ww.w;
    }
    style[gid] = s * INV_SQRT_LAT + bias[i];
  } else {
    int gid = (blockIdx.x - 16) * 256 + threadIdx.x;  // 131072 = 256*512
    int o = gid >> 9, i = gid & 511;
    const float* p = cw + (size_t)gid * 9;            // layout (o,i,3,3)
    float ss = 0.f, v[9];
#pragma unroll
    for (int t = 0; t < 9; ++t) { v[t] = p[t]; ss += v[t] * v[t]; }
    S[gid] = ss * (WSCALE * WSCALE);
#pragma unroll
    for (int t = 0; t < 9; ++t)
      w9[((size_t)(t * OUTCH + o)) * INCH + i] = f2bf(v[t] * WSCALE);
  }
}

// ---------------- stage 0c: demod[b,o] = rsqrt(sum_i style^2 * S + 1e-8)
__global__ void demod_k(const float* __restrict__ style, const float* __restrict__ S,
                        float* __restrict__ dmod) {
  int gid = blockIdx.x * 256 + threadIdx.x;       // 2048
  int b = gid >> 8, o = gid & 255;
  const float4* sv = (const float4*)(style + (size_t)b * INCH);
  const float4* Sv = (const float4*)(S + (size_t)o * INCH);
  float acc = 0.f;
#pragma unroll 4
  for (int l = 0; l < INCH / 4; ++l) {
    float4 st = sv[l], s2 = Sv[l];
    acc += st.x * st.x * s2.x + st.y * st.y * s2.y + st.z * st.z * s2.z + st.w * st.w * s2.w;
  }
  dmod[gid] = 1.0f / sqrtf(acc + 1e-8f);
}

// ---------------- stage 0d: xmt[b][s][i] = bf16(x[b][i][s] * style[b][i])   (transpose)
__global__ void modx_k(const float* __restrict__ x, const float* __restrict__ style,
                       unsigned short* __restrict__ xmt) {
  __shared__ float tile[32][33];
  int b = blockIdx.z;
  int s0 = blockIdx.x * 32;
  int i0 = blockIdx.y * 32;
  int c = threadIdx.x & 31, r = threadIdx.x >> 5;   // 32 x 8
#pragma unroll
  for (int p = 0; p < 4; ++p) {
    int ii = r + p * 8;
    tile[ii][c] = x[((size_t)(b * INCH + i0 + ii)) * SP + s0 + c] * style[b * INCH + i0 + ii];
  }
  __syncthreads();
#pragma unroll
  for (int p = 0; p < 4; ++p) {
    int ss = r + p * 8;
    xmt[((size_t)(b * SP + s0 + ss)) * INCH + i0 + c] = f2bf(tile[c][ss]);
  }
}

// ---------------- stage 1: T[m, n] = sum_k A[m,k] * B[n,k]
// 256x256 tile, BK=32, 512 thr (8 waves 2Mx4N), 4-deep LDS ring (4 x 32KB = 128 KiB).
// 2 phases per K-tile of 16 MFMA each. Tile t+3 staged during tile t (2 gloads/phase);
// end-of-tile wait is COUNTED vmcnt(8) (tiles t+2,t+3 stay in flight) -- never 0 until
// the 2-iteration tail peel. B-frags held in regs across both phases (no LDS re-read).
__global__ __launch_bounds__(512, 2)
void gemm_k(const unsigned short* __restrict__ A,   // MDIM x INCH
            const unsigned short* __restrict__ Bm,  // NB x SP x INCH
            unsigned short* __restrict__ C) {       // NB x MDIM x SP (bf16)
  __shared__ __align__(16) unsigned short lds[65536];  // A ring: 4x8192 elems @0; B ring @32768
  Bm += (size_t)blockIdx.z * SP * INCH;
  C  += (size_t)blockIdx.z * MDIM * SP;
  const int tid  = threadIdx.x;
  const int lane = tid & 63;
  const int wid  = tid >> 6;          // 0..7
  const int wr   = wid >> 2;          // 0..1 -> 128-row m-half
  const int wc   = wid & 3;           // 0..3 -> 64-col n-quarter
  const int m0 = blockIdx.y * 256;
  const int n0 = blockIdx.x * 256;
  const int r16  = lane & 15;
  const int quad = lane >> 4;

  // staging: LDS row = it*128 + (tid>>2), LDS chunk = tid&3 (linear dest for gload_lds);
  // global chunk pre-swizzled with s(row) = (row>>2)&3  (inverse == forward, XOR involution)
  const int srow = tid >> 2;                        // 0..127
  const int swb  = wid * 512;                       // wave-uniform LDS elem base
  const int sgch = ((tid & 3) ^ ((srow >> 2) & 3)) * 8;   // elems (same for it=0,1: 128>>2 ≡ 0 mod 4)

  f32x4 acc[8][4];
#pragma unroll
  for (int i = 0; i < 8; ++i)
#pragma unroll
    for (int j = 0; j < 4; ++j) acc[i][j] = (f32x4){0.f, 0.f, 0.f, 0.f};

#define STAGE_A(T) do {                                                             \
    unsigned short* _la = &lds[((T) & 3) * 8192 + swb];                             \
    const unsigned short* _ga = A + (size_t)(m0 + srow) * INCH + (T) * 32 + sgch;   \
    __builtin_amdgcn_global_load_lds(                                               \
        (const __attribute__((address_space(1))) void*)_ga,                         \
        (__attribute__((address_space(3))) void*)_la, 16, 0, 0);                    \
    __builtin_amdgcn_global_load_lds(                                               \
        (const __attribute__((address_space(1))) void*)(_ga + (size_t)128 * INCH),  \
        (__attribute__((address_space(3))) void*)(_la + 4096), 16, 0, 0);           \
  } while (0)

#define STAGE_B(T) do {                                                             \
    unsigned short* _lb = &lds[32768 + ((T) & 3) * 8192 + swb];                     \
    const unsigned short* _gb = Bm + (size_t)(n0 + srow) * INCH + (T) * 32 + sgch;  \
    __builtin_amdgcn_global_load_lds(                                               \
        (const __attribute__((address_space(1))) void*)_gb,                         \
        (__attribute__((address_space(3))) void*)_lb, 16, 0, 0);                    \
    __builtin_amdgcn_global_load_lds(                                               \
        (const __attribute__((address_space(1))) void*)(_gb + (size_t)128 * INCH),  \
        (__attribute__((address_space(3))) void*)(_lb + 4096), 16, 0, 0);           \
  } while (0)

  // read-side: frag row ra, k-chunk quad -> lds[ra*32 + ((quad ^ ((ra>>2)&3)) * 8)]
#define READ_A(PH) do {                                                             \
    _Pragma("unroll")                                                               \
    for (int _i = 0; _i < 4; ++_i) {                                                \
      const int _ra = wr * 128 + ((PH) * 4 + _i) * 16 + r16;                        \
      af[_i] = *(const bf16x8*)&As_[_ra * 32 + ((quad ^ ((_ra >> 2) & 3)) * 8)];    \
    }                                                                               \
  } while (0)

#define READ_B() do {                                                               \
    _Pragma("unroll")                                                               \
    for (int _j = 0; _j < 4; ++_j) {                                                \
      const int _rb = wc * 64 + _j * 16 + r16;                                      \
      bfv[_j] = *(const bf16x8*)&Bs_[_rb * 32 + ((quad ^ ((_rb >> 2) & 3)) * 8)];   \
    }                                                                               \
  } while (0)

#define MFMA_PH(PH) do {                                                            \
    __builtin_amdgcn_s_setprio(1);                                                  \
    _Pragma("unroll")                                                               \
    for (int _i = 0; _i < 4; ++_i)                                                  \
    _Pragma("unroll")                                                               \
    for (int _j = 0; _j < 4; ++_j)                                                  \
      acc[(PH) * 4 + _i][_j] = __builtin_amdgcn_mfma_f32_16x16x32_bf16(             \
          af[_i], bfv[_j], acc[(PH) * 4 + _i][_j], 0, 0, 0);                        \
    __builtin_amdgcn_s_setprio(0);                                                  \
  } while (0)

  // prologue: stage tiles 0,1,2 (12 loads/wave); wait tile 0 (counted), barrier
  STAGE_A(0); STAGE_B(0);
  STAGE_A(1); STAGE_B(1);
  STAGE_A(2); STAGE_B(2);
  asm volatile("s_waitcnt vmcnt(8)" ::: "memory");
  __builtin_amdgcn_sched_barrier(0);
  __builtin_amdgcn_s_barrier();

  for (int t = 0; t < 16; ++t) {
    const unsigned short* As_ = &lds[(t & 3) * 8192];
    const unsigned short* Bs_ = &lds[32768 + (t & 3) * 8192];
    bf16x8 af[4], bfv[4];
    // phase 1: stage A of tile t+3 (buf freed at end of tile t-1); read A0-3,B0-3; MFMA i=0..3
    if (t + 3 < 16) STAGE_A(t + 3);
    READ_A(0);
    READ_B();
    __builtin_amdgcn_s_barrier();
    MFMA_PH(0);
    __builtin_amdgcn_s_barrier();
    // phase 2: stage B of tile t+3; read A4-7 (B held in regs); MFMA i=4..7
    if (t + 3 < 16) STAGE_B(t + 3);
    READ_A(1);
    __builtin_amdgcn_s_barrier();
    MFMA_PH(1);
    // end-of-tile wait: tile t+1 must be resident; tiles t+2,t+3 stay in flight.
    if (t < 13) {
      asm volatile("s_waitcnt vmcnt(8)" ::: "memory");
      __builtin_amdgcn_sched_barrier(0);
    } else if (t == 13) {
      asm volatile("s_waitcnt vmcnt(4)" ::: "memory");
      __builtin_amdgcn_sched_barrier(0);
    } else if (t == 14) {
      asm volatile("s_waitcnt vmcnt(0)" ::: "memory");
      __builtin_amdgcn_sched_barrier(0);
    }
    __builtin_amdgcn_s_barrier();
  }
#undef STAGE_A
#undef STAGE_B
#undef READ_A
#undef READ_B
#undef MFMA_PH

  // epilogue: restage full 256x256 bf16 tile in LDS (chunk-XOR swizzle), then dwordx4 stores.
  // C/D layout col=lane&15, row=quad*4+reg [m89].
#pragma unroll
  for (int i = 0; i < 8; ++i)
#pragma unroll
    for (int j = 0; j < 4; ++j)
#pragma unroll
      for (int r = 0; r < 4; ++r) {
        int row = wr * 128 + i * 16 + quad * 4 + r;
        int col = wc * 64 + j * 16 + r16;
        int pc  = (col >> 3) ^ (row & 31);
        lds[row * 256 + pc * 8 + (col & 7)] = f2bf(acc[i][j][r]);
      }
  __syncthreads();
#pragma unroll
  for (int rr = 0; rr < 16; ++rr) {
    int row = rr * 16 + (tid >> 5);
    int c   = tid & 31;
    int pc  = c ^ (row & 31);
    uint4 v = *(const uint4*)&lds[row * 256 + pc * 8];
    *(uint4*)&C[(size_t)(m0 + row) * SP + n0 + c * 8] = v;
  }
}

// ---------------- stage 2: separable parity-combine + 4x4 blur + demod
// Block = (strip of 8 Y-rows, o, b). LDS 27.9KB -> 5 blocks/CU.
// TlB (bf16): rows (tap,ry) ry=0..9 (Yg=Y0-1..Y0+8), col 4 == x=0, stride 70.
// V (fp32): [c][10 rows][32 chunks of 4], stride 128 exactly, XOR chunk swizzle
//   p = (l & ~3) | ((l&3) ^ ((l>>3)&3))  -- conflict-free for both writers and readers.
#define STRIP 8
#define TLSTR 70
#define TLROWS 10
__global__ __launch_bounds__(256)
void combine_k(const unsigned short* __restrict__ T, const float* __restrict__ dm,
               float* __restrict__ out) {
  __shared__ __align__(16) unsigned short TlB[9 * TLROWS * TLSTR + 4];  // 12608 B
  __shared__ __align__(16) float V[3 * TLROWS * 128];                   // 15360 B
  T   += (size_t)blockIdx.z * MDIM * SP;
  dm  += (size_t)blockIdx.z * OUTCH;
  out += (size_t)blockIdx.z * OUTCH * 128 * 128;
  const int o  = blockIdx.y;
  const int Y0 = blockIdx.x * STRIP;
  const int tid = threadIdx.x;

  // zero-fill TlB (halo rows/cols must read 0)
  {
    uint4* tz = (uint4*)TlB;
#pragma unroll
    for (int idx = tid; idx < 788; idx += 256) tz[idx] = (uint4){0u, 0u, 0u, 0u};
  }
  __syncthreads();

  // tap load: 9 taps x 10 rows x 64 cols as ushort4 chunks; 1440 ops
  for (int idx = tid; idx < 1440; idx += 256) {
    int tap = idx / 160;
    int rem = idx - tap * 160;
    int ry  = rem >> 4;
    int c16 = rem & 15;
    int Yg = Y0 - 1 + ry;
    if ((unsigned)Yg < 64u) {
      ushort4 v4 = *(const ushort4*)(T + (size_t)(tap * OUTCH + o) * SP + Yg * 64 + c16 * 4);
      unsigned short* dst = &TlB[(tap * TLROWS + ry) * TLSTR + 4 + c16 * 4];
      *(ushort2*)(dst)     = make_ushort2(v4.x, v4.y);
      *(ushort2*)(dst + 2) = make_ushort2(v4.z, v4.w);
    }
  }
  __syncthreads();

  // x-pass: 30 row-tasks (c 0..2, yr 0..9) x 8 x-chunks of 8 -> V
  {
    const int r  = tid >> 3;
    const int xc = tid & 7;
    if (r < 30) {
      const int c  = r / 10;
      const int yr = r - c * 10;
      const int X0 = xc * 8;
      float td[3][12];
#pragma unroll
      for (int d = 0; d < 3; ++d) {
        const unsigned short* src = &TlB[((c * 3 + d) * TLROWS + yr) * TLSTR + 2 + X0];
#pragma unroll
        for (int k = 0; k < 6; ++k) {
          ushort2 u2 = *(const ushort2*)(src + 2 * k);
          td[d][2 * k]     = bf2f(u2.x);
          td[d][2 * k + 1] = bf2f(u2.y);
        }
      }
      float vout[16];
#pragma unroll
      for (int Xl = 0; Xl < 8; ++Xl) {
        float a0 = td[0][Xl + 1], a1 = td[0][Xl + 2], a2 = td[0][Xl + 3];
        float b0 = td[1][Xl + 1], b1 = td[1][Xl + 2], b2 = td[1][Xl + 3];
        float c0 = td[2][Xl + 1], c1 = td[2][Xl + 2], c2 = td[2][Xl + 3];
        vout[2 * Xl]     = b0 + 3.f * c0 + 3.f * a1 + 3.f * b1 + c1 + a2;
        vout[2 * Xl + 1] = c0 + a1 + 3.f * b1 + 3.f * c1 + 3.f * a2 + b2;
      }
      float* vr = &V[(c * TLROWS + yr) * 128];
#pragma unroll
      for (int j = 0; j < 4; ++j) {
        int l = 4 * xc + j;
        int p = (l & ~3) | ((l & 3) ^ ((l >> 3) & 3));
        *(f32x4*)(vr + p * 4) = (f32x4){vout[4 * j], vout[4 * j + 1], vout[4 * j + 2], vout[4 * j + 3]};
      }
    }
  }
  __syncthreads();

  // y-pass: 16 out rows x 32 chunks; thread = (y=tid>>4, chunk tid&15 + 16*xg)
  {
    const int y  = tid >> 4;        // 0..15
    const int py = y & 1;
    const int Yl = y >> 1;          // 0..7
    const float dmv = dm[o] * (1.0f / 16.0f);
    float* orow = out + ((size_t)o * 128 + (Y0 * 2 + y)) * 128;
#pragma unroll
    for (int xg = 0; xg < 2; ++xg) {
      int l = (tid & 15) + 16 * xg;
      int p = (l & ~3) | ((l & 3) ^ ((l >> 3) & 3));
      int off = p * 4;
      f32x4 v00 = *(const f32x4*)&V[((0 * TLROWS) + Yl + 0) * 128 + off];
      f32x4 v01 = *(const f32x4*)&V[((0 * TLROWS) + Yl + 1) * 128 + off];
      f32x4 v02 = *(const f32x4*)&V[((0 * TLROWS) + Yl + 2) * 128 + off];
      f32x4 v10 = *(const f32x4*)&V[((1 * TLROWS) + Yl + 0) * 128 + off];
      f32x4 v11 = *(const f32x4*)&V[((1 * TLROWS) + Yl + 1) * 128 + off];
      f32x4 v12 = *(const f32x4*)&V[((1 * TLROWS) + Yl + 2) * 128 + off];
      f32x4 v20 = *(const f32x4*)&V[((2 * TLROWS) + Yl + 0) * 128 + off];
      f32x4 v21 = *(const f32x4*)&V[((2 * TLROWS) + Yl + 1) * 128 + off];
      f32x4 v22 = *(const f32x4*)&V[((2 * TLROWS) + Yl + 2) * 128 + off];
      f32x4 r;
      if (py == 0)
        r = v10 + 3.f * v20 + 3.f * v01 + 3.f * v11 + v21 + v02;
      else
        r = v20 + v01 + 3.f * v11 + 3.f * v21 + 3.f * v02 + v12;
      r *= dmv;
      *(f32x4*)(orow + l * 4) = r;
    }
  }
}

extern "C" void kernel_launch(void* const* d_in, const int* in_sizes, int n_in,
                              void* d_out, int out_size, void* d_ws, size_t ws_size,
                              hipStream_t stream) {
  const float* x    = (const float*)d_in[0];
  const float* w    = (const float*)d_in[1];
  const float* aff  = (const float*)d_in[2];
  const float* bias = (const float*)d_in[3];
  const float* cw   = (const float*)d_in[4];
  float* out = (float*)d_out;
  char* ws = (char*)d_ws;
  // ws layout: style 16K | S 512K | demod 8K | w9 2.25M | xmt 32M | T(bf16) 151M
  float* style        = (float*)(ws);
  float* S            = (float*)(ws + 16384);
  float* dmod         = (float*)(ws + 540672);
  unsigned short* w9  = (unsigned short*)(ws + 548864);
  unsigned short* xmt = (unsigned short*)(ws + 2908160);
  unsigned short* T   = (unsigned short*)(ws + 36462592);

  hipLaunchKernelGGL(prep_k, dim3(528), dim3(256), 0, stream, w, aff, bias, style, cw, S, w9);
  hipLaunchKernelGGL(demod_k, dim3(8), dim3(256), 0, stream, style, S, dmod);
  hipLaunchKernelGGL(modx_k, dim3(128, 16, 8), dim3(256), 0, stream, x, style, xmt);
  hipLaunchKernelGGL(gemm_k, dim3(16, 9, NB), dim3(512), 0, stream, w9, xmt, T);
  hipLaunchKernelGGL(combine_k, dim3(64 / STRIP, 256, NB), dim3(256), 0, stream, T, dmod, out);
}

// Round 3
// 396.397 us; speedup vs baseline: 1.0411x; 1.0411x over previous
//
#include <hip/hip_runtime.h>
#include <hip/hip_bf16.h>
#include <math.h>

#define NB 8
#define INCH 512
#define OUTCH 256
#define SP 4096          // 64*64 spatial
#define LAT 512
#define NTAP 9
#define MDIM (NTAP*OUTCH)   // 2304

#define INV_SQRT_LAT 0.044194173824159216f   // 1/sqrt(512)
#define WSCALE 0.014731391274719738f         // 1/sqrt(512*9)

typedef __bf16 bf16x8 __attribute__((ext_vector_type(8)));
typedef float  f32x4  __attribute__((ext_vector_type(4)));

__device__ __forceinline__ unsigned short f2bf(float f) {
  unsigned u = __float_as_uint(f);
  u += 0x7fffu + ((u >> 16) & 1u);       // round-to-nearest-even
  return (unsigned short)(u >> 16);
}
__device__ __forceinline__ float bf2f(unsigned short v) {
  return __uint_as_float((unsigned)v << 16);
}

// ---------------- stage 0a+0b fused: style GEMV (blocks 0..15) + weight prep (blocks 16..527)
__global__ void prep_k(const float* __restrict__ w, const float* __restrict__ aff,
                       const float* __restrict__ bias, float* __restrict__ style,
                       const float* __restrict__ cw, float* __restrict__ S,
                       unsigned short* __restrict__ w9) {
  if (blockIdx.x < 16) {
    int gid = blockIdx.x * 256 + threadIdx.x;       // 4096
    int b = gid >> 9, i = gid & 511;
    const float4* wv = (const float4*)(w + (size_t)b * LAT);
    const float4* av = (const float4*)(aff + (size_t)i * LAT);
    float s = 0.f;
#pragma unroll 4
    for (int l = 0; l < LAT / 4; ++l) {
      float4 a = av[l], ww = wv[l];
      s += a.x * ww.x + a.y * ww.y + a.z * ww.z + a.w * ww.w;
    }
    style[gid] = s * INV_SQRT_LAT + bias[i];
  } else {
    int gid = (blockIdx.x - 16) * 256 + threadIdx.x;  // 131072 = 256*512
    int o = gid >> 9, i = gid & 511;
    const float* p = cw + (size_t)gid * 9;            // layout (o,i,3,3)
    float ss = 0.f, v[9];
#pragma unroll
    for (int t = 0; t < 9; ++t) { v[t] = p[t]; ss += v[t] * v[t]; }
    S[gid] = ss * (WSCALE * WSCALE);
#pragma unroll
    for (int t = 0; t < 9; ++t)
      w9[((size_t)(t * OUTCH + o)) * INCH + i] = f2bf(v[t] * WSCALE);
  }
}

// ---------------- stage 0c: demod[b,o] = rsqrt(sum_i style^2 * S + 1e-8)
__global__ void demod_k(const float* __restrict__ style, const float* __restrict__ S,
                        float* __restrict__ dmod) {
  int gid = blockIdx.x * 256 + threadIdx.x;       // 2048
  int b = gid >> 8, o = gid & 255;
  const float4* sv = (const float4*)(style + (size_t)b * INCH);
  const float4* Sv = (const float4*)(S + (size_t)o * INCH);
  float acc = 0.f;
#pragma unroll 4
  for (int l = 0; l < INCH / 4; ++l) {
    float4 st = sv[l], s2 = Sv[l];
    acc += st.x * st.x * s2.x + st.y * st.y * s2.y + st.z * st.z * s2.z + st.w * st.w * s2.w;
  }
  dmod[gid] = 1.0f / sqrtf(acc + 1e-8f);
}

// ---------------- stage 0d: xmt[b][s][i] = bf16(x[b][i][s] * style[b][i])   (transpose)
__global__ void modx_k(const float* __restrict__ x, const float* __restrict__ style,
                       unsigned short* __restrict__ xmt) {
  __shared__ float tile[32][33];
  int b = blockIdx.z;
  int s0 = blockIdx.x * 32;
  int i0 = blockIdx.y * 32;
  int c = threadIdx.x & 31, r = threadIdx.x >> 5;   // 32 x 8
#pragma unroll
  for (int p = 0; p < 4; ++p) {
    int ii = r + p * 8;
    tile[ii][c] = x[((size_t)(b * INCH + i0 + ii)) * SP + s0 + c] * style[b * INCH + i0 + ii];
  }
  __syncthreads();
#pragma unroll
  for (int p = 0; p < 4; ++p) {
    int ss = r + p * 8;
    xmt[((size_t)(b * SP + s0 + ss)) * INCH + i0 + c] = f2bf(tile[c][ss]);
  }
}

// ---------------- stage 1: T[m, n] = sum_k A[m,k] * B[n,k]
// BM=256 BN=128 BK=64, 512 thr (8 waves 4Mx2N, 64x64/wave), 3-deep LDS ring (3x48KB=144KB).
// Proven zero-conflict BK=64 chunk-XOR swizzle (round-1 layout). Tile t+2 staged during
// tile t (6 gloads/wave spread over 4 phases); end-of-tile wait is COUNTED vmcnt(6)
// (tile t+2 stays in flight) -- drains to 0 only at the tail. 4 phases x 8 MFMA.
// NOTE (round-2 lesson): BK=32 rows (64B) alias bank cycles pairwise -> 7M conflicts;
// BK=64 rows (128B = exactly 32 banks) with ch = (quad4+kk) ^ (row&7) measured 0.
__global__ __launch_bounds__(512, 2)
void gemm_k(const unsigned short* __restrict__ A,   // MDIM x INCH
            const unsigned short* __restrict__ Bm,  // NB x SP x INCH
            unsigned short* __restrict__ C) {       // NB x MDIM x SP (bf16)
  // ring: A[r] elems [r*16384, +16384) ; B[r] elems [49152 + r*8192, +8192)
  __shared__ __align__(16) unsigned short lds[73728];  // 147456 B
  Bm += (size_t)blockIdx.z * SP * INCH;
  C  += (size_t)blockIdx.z * MDIM * SP;
  const int tid  = threadIdx.x;
  const int lane = tid & 63;
  const int wid  = tid >> 6;          // 0..7
  const int wm   = (wid >> 1) * 64;   // m-offset of wave tile
  const int wn   = (wid & 1) * 64;    // n-offset of wave tile
  const int m0 = blockIdx.y * 256;
  const int n0 = blockIdx.x * 128;
  const int r16  = lane & 15;
  const int quad = lane >> 4;

  // staging addressing (round-1 proven): thread -> row tid>>3 (0..63), LDS chunk tid&7,
  // global chunk pre-swizzled: sgch = ((tid&7) ^ (srow&7)) * 8 elems.
  const int srow = tid >> 3;
  const int sgch = ((tid & 7) ^ (srow & 7)) * 8;
  const int swb  = wid * 512;                       // wave-uniform LDS elem base (8 rows * 64)

  f32x4 acc[4][4];
#pragma unroll
  for (int i = 0; i < 4; ++i)
#pragma unroll
    for (int j = 0; j < 4; ++j) acc[i][j] = (f32x4){0.f, 0.f, 0.f, 0.f};

  // A tile: 256 rows x 64 -> 4 gloads (it=0..3); B tile: 128 rows x 64 -> 2 gloads.
#define STAGE_A2(T, IT0) do {                                                       \
    unsigned short* _la = &lds[(((T) % 3) * 16384) + swb];                          \
    const unsigned short* _ga = A + (size_t)(m0 + srow) * INCH + (T) * 64 + sgch;   \
    _Pragma("unroll")                                                               \
    for (int _it = (IT0); _it < (IT0) + 2; ++_it)                                   \
      __builtin_amdgcn_global_load_lds(                                             \
          (const __attribute__((address_space(1))) void*)(_ga + (size_t)_it * 64 * INCH), \
          (__attribute__((address_space(3))) void*)(_la + _it * 4096), 16, 0, 0);   \
  } while (0)

#define STAGE_B1(T, IT) do {                                                        \
    unsigned short* _lb = &lds[49152 + (((T) % 3) * 8192) + swb];                   \
    const unsigned short* _gb = Bm + (size_t)(n0 + (IT) * 64 + srow) * INCH + (T) * 64 + sgch; \
    __builtin_amdgcn_global_load_lds(                                               \
        (const __attribute__((address_space(1))) void*)_gb,                         \
        (__attribute__((address_space(3))) void*)(_lb + (IT) * 4096), 16, 0, 0);    \
  } while (0)

  // fragment reads: row r in tile, k-chunk (kk*4+quad) ^ (r&7)
#define READ_A(MH) do {                                                             \
    _Pragma("unroll")                                                               \
    for (int _i = 0; _i < 2; ++_i) {                                                \
      const int _ra = wm + ((MH) * 2 + _i) * 16 + r16;                              \
      af[0][_i] = *(const bf16x8*)&As_[_ra * 64 + (((0 + quad) ^ (_ra & 7)) * 8)];  \
      af[1][_i] = *(const bf16x8*)&As_[_ra * 64 + (((4 + quad) ^ (_ra & 7)) * 8)];  \
    }                                                                               \
  } while (0)

#define READ_B(NH) do {                                                             \
    _Pragma("unroll")                                                               \
    for (int _j = 0; _j < 2; ++_j) {                                                \
      const int _rb = wn + ((NH) * 2 + _j) * 16 + r16;                              \
      bfv[0][_j] = *(const bf16x8*)&Bs_[_rb * 64 + (((0 + quad) ^ (_rb & 7)) * 8)]; \
      bfv[1][_j] = *(const bf16x8*)&Bs_[_rb * 64 + (((4 + quad) ^ (_rb & 7)) * 8)]; \
    }                                                                               \
  } while (0)

#define MFMA_Q(MH, NH) do {                                                         \
    __builtin_amdgcn_s_setprio(1);                                                  \
    _Pragma("unroll")                                                               \
    for (int _kk = 0; _kk < 2; ++_kk)                                               \
    _Pragma("unroll")                                                               \
    for (int _i = 0; _i < 2; ++_i)                                                  \
    _Pragma("unroll")                                                               \
    for (int _j = 0; _j < 2; ++_j)                                                  \
      acc[(MH)*2+_i][(NH)*2+_j] = __builtin_amdgcn_mfma_f32_16x16x32_bf16(          \
          af[_kk][_i], bfv[_kk][_j], acc[(MH)*2+_i][(NH)*2+_j], 0, 0, 0);           \
    __builtin_amdgcn_s_setprio(0);                                                  \
  } while (0)

  // prologue: stage tiles 0 and 1 (12 loads/wave); counted wait for tile 0 only.
  STAGE_A2(0, 0); STAGE_A2(0, 2); STAGE_B1(0, 0); STAGE_B1(0, 1);
  STAGE_A2(1, 0); STAGE_A2(1, 2); STAGE_B1(1, 0); STAGE_B1(1, 1);
  asm volatile("s_waitcnt vmcnt(6)" ::: "memory");
  __builtin_amdgcn_sched_barrier(0);
  __builtin_amdgcn_s_barrier();

  for (int t = 0; t < 8; ++t) {
    const unsigned short* As_ = &lds[(t % 3) * 16384];
    const unsigned short* Bs_ = &lds[49152 + (t % 3) * 8192];
    const bool st = (t < 6);
    bf16x8 af[2][2], bfv[2][2];
    // phase 1: quadrant (0,0); stage A[t+2] rows 0..127
    if (st) STAGE_A2(t + 2, 0);
    READ_A(0); READ_B(0);
    __builtin_amdgcn_s_barrier();
    MFMA_Q(0, 0);
    __builtin_amdgcn_s_barrier();
    // phase 2: quadrant (0,1); stage A[t+2] rows 128..255
    if (st) STAGE_A2(t + 2, 2);
    READ_B(1);
    __builtin_amdgcn_s_barrier();
    MFMA_Q(0, 1);
    __builtin_amdgcn_s_barrier();
    // phase 3: quadrant (1,1); stage B[t+2] rows 0..63
    if (st) STAGE_B1(t + 2, 0);
    READ_A(1);
    __builtin_amdgcn_s_barrier();
    MFMA_Q(1, 1);
    __builtin_amdgcn_s_barrier();
    // phase 4: quadrant (1,0); stage B[t+2] rows 64..127
    if (st) STAGE_B1(t + 2, 1);
    READ_B(0);
    __builtin_amdgcn_s_barrier();
    MFMA_Q(1, 0);
    // end-of-tile: tile t+1 must be resident; keep tile t+2 in flight (counted).
    if (t < 6) {
      asm volatile("s_waitcnt vmcnt(6)" ::: "memory");
      __builtin_amdgcn_sched_barrier(0);
    } else if (t == 6) {
      asm volatile("s_waitcnt vmcnt(0)" ::: "memory");
      __builtin_amdgcn_sched_barrier(0);
    }
    __builtin_amdgcn_s_barrier();
  }
#undef STAGE_A2
#undef STAGE_B1
#undef READ_A
#undef READ_B
#undef MFMA_Q

  // epilogue: restage 256x128 bf16 tile in LDS (16-chunk XOR swizzle per 256B row), store x4.
  // C/D layout col=lane&15, row=quad*4+reg [m89].
#pragma unroll
  for (int i = 0; i < 4; ++i)
#pragma unroll
    for (int j = 0; j < 4; ++j)
#pragma unroll
      for (int r = 0; r < 4; ++r) {
        int row = wm + i * 16 + quad * 4 + r;
        int col = wn + j * 16 + r16;
        int pc  = (col >> 3) ^ (row & 15);
        lds[row * 128 + pc * 8 + (col & 7)] = f2bf(acc[i][j][r]);
      }
  __syncthreads();
#pragma unroll
  for (int rr = 0; rr < 8; ++rr) {
    int row = rr * 32 + (tid >> 4);
    int c   = tid & 15;
    int pc  = c ^ (row & 15);
    uint4 v = *(const uint4*)&lds[row * 128 + pc * 8];
    *(uint4*)&C[(size_t)(m0 + row) * SP + n0 + c * 8] = v;
  }
}

// ---------------- stage 2: separable parity-combine + 4x4 blur + demod
// Block = (strip of 8 Y-rows, o, b). LDS 27.9KB -> 5 blocks/CU.
// TlB (bf16): rows (tap,ry) ry=0..9 (Yg=Y0-1..Y0+8), col 4 == x=0, stride 70.
// V (fp32): [c][10 rows][32 chunks of 4], stride 128 exactly, XOR chunk swizzle
//   p = (l & ~3) | ((l&3) ^ ((l>>3)&3))  -- conflict-free for both writers and readers.
#define STRIP 8
#define TLSTR 70
#define TLROWS 10
__global__ __launch_bounds__(256)
void combine_k(const unsigned short* __restrict__ T, const float* __restrict__ dm,
               float* __restrict__ out) {
  __shared__ __align__(16) unsigned short TlB[9 * TLROWS * TLSTR + 4];  // 12608 B
  __shared__ __align__(16) float V[3 * TLROWS * 128];                   // 15360 B
  T   += (size_t)blockIdx.z * MDIM * SP;
  dm  += (size_t)blockIdx.z * OUTCH;
  out += (size_t)blockIdx.z * OUTCH * 128 * 128;
  const int o  = blockIdx.y;
  const int Y0 = blockIdx.x * STRIP;
  const int tid = threadIdx.x;

  // zero-fill TlB (halo rows/cols must read 0)
  {
    uint4* tz = (uint4*)TlB;
#pragma unroll
    for (int idx = tid; idx < 788; idx += 256) tz[idx] = (uint4){0u, 0u, 0u, 0u};
  }
  __syncthreads();

  // tap load: 9 taps x 10 rows x 64 cols as ushort4 chunks; 1440 ops
  for (int idx = tid; idx < 1440; idx += 256) {
    int tap = idx / 160;
    int rem = idx - tap * 160;
    int ry  = rem >> 4;
    int c16 = rem & 15;
    int Yg = Y0 - 1 + ry;
    if ((unsigned)Yg < 64u) {
      ushort4 v4 = *(const ushort4*)(T + (size_t)(tap * OUTCH + o) * SP + Yg * 64 + c16 * 4);
      unsigned short* dst = &TlB[(tap * TLROWS + ry) * TLSTR + 4 + c16 * 4];
      *(ushort2*)(dst)     = make_ushort2(v4.x, v4.y);
      *(ushort2*)(dst + 2) = make_ushort2(v4.z, v4.w);
    }
  }
  __syncthreads();

  // x-pass: 30 row-tasks (c 0..2, yr 0..9) x 8 x-chunks of 8 -> V
  {
    const int r  = tid >> 3;
    const int xc = tid & 7;
    if (r < 30) {
      const int c  = r / 10;
      const int yr = r - c * 10;
      const int X0 = xc * 8;
      float td[3][12];
#pragma unroll
      for (int d = 0; d < 3; ++d) {
        const unsigned short* src = &TlB[((c * 3 + d) * TLROWS + yr) * TLSTR + 2 + X0];
#pragma unroll
        for (int k = 0; k < 6; ++k) {
          ushort2 u2 = *(const ushort2*)(src + 2 * k);
          td[d][2 * k]     = bf2f(u2.x);
          td[d][2 * k + 1] = bf2f(u2.y);
        }
      }
      float vout[16];
#pragma unroll
      for (int Xl = 0; Xl < 8; ++Xl) {
        float a0 = td[0][Xl + 1], a1 = td[0][Xl + 2], a2 = td[0][Xl + 3];
        float b0 = td[1][Xl + 1], b1 = td[1][Xl + 2], b2 = td[1][Xl + 3];
        float c0 = td[2][Xl + 1], c1 = td[2][Xl + 2], c2 = td[2][Xl + 3];
        vout[2 * Xl]     = b0 + 3.f * c0 + 3.f * a1 + 3.f * b1 + c1 + a2;
        vout[2 * Xl + 1] = c0 + a1 + 3.f * b1 + 3.f * c1 + 3.f * a2 + b2;
      }
      float* vr = &V[(c * TLROWS + yr) * 128];
#pragma unroll
      for (int j = 0; j < 4; ++j) {
        int l = 4 * xc + j;
        int p = (l & ~3) | ((l & 3) ^ ((l >> 3) & 3));
        *(f32x4*)(vr + p * 4) = (f32x4){vout[4 * j], vout[4 * j + 1], vout[4 * j + 2], vout[4 * j + 3]};
      }
    }
  }
  __syncthreads();

  // y-pass: 16 out rows x 32 chunks; thread = (y=tid>>4, chunk tid&15 + 16*xg)
  {
    const int y  = tid >> 4;        // 0..15
    const int py = y & 1;
    const int Yl = y >> 1;          // 0..7
    const float dmv = dm[o] * (1.0f / 16.0f);
    float* orow = out + ((size_t)o * 128 + (Y0 * 2 + y)) * 128;
#pragma unroll
    for (int xg = 0; xg < 2; ++xg) {
      int l = (tid & 15) + 16 * xg;
      int p = (l & ~3) | ((l & 3) ^ ((l >> 3) & 3));
      int off = p * 4;
      f32x4 v00 = *(const f32x4*)&V[((0 * TLROWS) + Yl + 0) * 128 + off];
      f32x4 v01 = *(const f32x4*)&V[((0 * TLROWS) + Yl + 1) * 128 + off];
      f32x4 v02 = *(const f32x4*)&V[((0 * TLROWS) + Yl + 2) * 128 + off];
      f32x4 v10 = *(const f32x4*)&V[((1 * TLROWS) + Yl + 0) * 128 + off];
      f32x4 v11 = *(const f32x4*)&V[((1 * TLROWS) + Yl + 1) * 128 + off];
      f32x4 v12 = *(const f32x4*)&V[((1 * TLROWS) + Yl + 2) * 128 + off];
      f32x4 v20 = *(const f32x4*)&V[((2 * TLROWS) + Yl + 0) * 128 + off];
      f32x4 v21 = *(const f32x4*)&V[((2 * TLROWS) + Yl + 1) * 128 + off];
      f32x4 v22 = *(const f32x4*)&V[((2 * TLROWS) + Yl + 2) * 128 + off];
      f32x4 r;
      if (py == 0)
        r = v10 + 3.f * v20 + 3.f * v01 + 3.f * v11 + v21 + v02;
      else
        r = v20 + v01 + 3.f * v11 + 3.f * v21 + 3.f * v02 + v12;
      r *= dmv;
      *(f32x4*)(orow + l * 4) = r;
    }
  }
}

extern "C" void kernel_launch(void* const* d_in, const int* in_sizes, int n_in,
                              void* d_out, int out_size, void* d_ws, size_t ws_size,
                              hipStream_t stream) {
  const float* x    = (const float*)d_in[0];
  const float* w    = (const float*)d_in[1];
  const float* aff  = (const float*)d_in[2];
  const float* bias = (const float*)d_in[3];
  const float* cw   = (const float*)d_in[4];
  float* out = (float*)d_out;
  char* ws = (char*)d_ws;
  // ws layout: style 16K | S 512K | demod 8K | w9 2.25M | xmt 32M | T(bf16) 151M
  float* style        = (float*)(ws);
  float* S            = (float*)(ws + 16384);
  float* dmod         = (float*)(ws + 540672);
  unsigned short* w9  = (unsigned short*)(ws + 548864);
  unsigned short* xmt = (unsigned short*)(ws + 2908160);
  unsigned short* T   = (unsigned short*)(ws + 36462592);

  hipLaunchKernelGGL(prep_k, dim3(528), dim3(256), 0, stream, w, aff, bias, style, cw, S, w9);
  hipLaunchKernelGGL(demod_k, dim3(8), dim3(256), 0, stream, style, S, dmod);
  hipLaunchKernelGGL(modx_k, dim3(128, 16, 8), dim3(256), 0, stream, x, style, xmt);
  hipLaunchKernelGGL(gemm_k, dim3(32, 9, NB), dim3(512), 0, stream, w9, xmt, T);
  hipLaunchKernelGGL(combine_k, dim3(64 / STRIP, 256, NB), dim3(256), 0, stream, T, dmod, out);
}

// Round 4
// 385.178 us; speedup vs baseline: 1.0714x; 1.0291x over previous
//
#include <hip/hip_runtime.h>
#include <hip/hip_bf16.h>
#include <math.h>

#define NB 8
#define INCH 512
#define OUTCH 256
#define SP 4096          // 64*64 spatial
#define LAT 512
#define NTAP 9
#define MDIM (NTAP*OUTCH)   // 2304

#define INV_SQRT_LAT 0.044194173824159216f   // 1/sqrt(512)
#define WSCALE 0.014731391274719738f         // 1/sqrt(512*9)

typedef __bf16 bf16x8 __attribute__((ext_vector_type(8)));
typedef float  f32x4  __attribute__((ext_vector_type(4)));

__device__ __forceinline__ unsigned short f2bf(float f) {
  unsigned u = __float_as_uint(f);
  u += 0x7fffu + ((u >> 16) & 1u);       // round-to-nearest-even
  return (unsigned short)(u >> 16);
}
__device__ __forceinline__ float bf2f(unsigned short v) {
  return __uint_as_float((unsigned)v << 16);
}

// ---------------- stage 0a+0b fused: style GEMV (blocks 0..15) + weight prep (blocks 16..527)
__global__ void prep_k(const float* __restrict__ w, const float* __restrict__ aff,
                       const float* __restrict__ bias, float* __restrict__ style,
                       const float* __restrict__ cw, float* __restrict__ S,
                       unsigned short* __restrict__ w9) {
  if (blockIdx.x < 16) {
    int gid = blockIdx.x * 256 + threadIdx.x;       // 4096
    int b = gid >> 9, i = gid & 511;
    const float4* wv = (const float4*)(w + (size_t)b * LAT);
    const float4* av = (const float4*)(aff + (size_t)i * LAT);
    float s = 0.f;
#pragma unroll 4
    for (int l = 0; l < LAT / 4; ++l) {
      float4 a = av[l], ww = wv[l];
      s += a.x * ww.x + a.y * ww.y + a.z * ww.z + a.w * ww.w;
    }
    style[gid] = s * INV_SQRT_LAT + bias[i];
  } else {
    int gid = (blockIdx.x - 16) * 256 + threadIdx.x;  // 131072 = 256*512
    int o = gid >> 9, i = gid & 511;
    const float* p = cw + (size_t)gid * 9;            // layout (o,i,3,3)
    float ss = 0.f, v[9];
#pragma unroll
    for (int t = 0; t < 9; ++t) { v[t] = p[t]; ss += v[t] * v[t]; }
    S[gid] = ss * (WSCALE * WSCALE);
#pragma unroll
    for (int t = 0; t < 9; ++t)
      w9[((size_t)(t * OUTCH + o)) * INCH + i] = f2bf(v[t] * WSCALE);
  }
}

// ---------------- stage 0c: demod[b,o] = rsqrt(sum_i style^2 * S + 1e-8)
// v2: 16 threads per output, 128 blocks (was 8 blocks -> 248 CUs idle).
__global__ void demod_k(const float* __restrict__ style, const float* __restrict__ S,
                        float* __restrict__ dmod) {
  int g = blockIdx.x * 16 + (threadIdx.x >> 4);    // 2048 outputs
  int j = threadIdx.x & 15;
  int b = g >> 8, o = g & 255;
  const float4* sv = (const float4*)(style + (size_t)b * INCH + j * 32);
  const float4* Sv = (const float4*)(S + (size_t)o * INCH + j * 32);
  float acc = 0.f;
#pragma unroll
  for (int l = 0; l < 8; ++l) {
    float4 st = sv[l], s2 = Sv[l];
    acc += st.x * st.x * s2.x + st.y * st.y * s2.y + st.z * st.z * s2.z + st.w * st.w * s2.w;
  }
#pragma unroll
  for (int d = 1; d < 16; d <<= 1) acc += __shfl_xor(acc, d, 16);
  if (j == 0) dmod[g] = 1.0f / sqrtf(acc + 1e-8f);
}

// ---------------- stage 0d: xmt[b][s][i] = bf16(x[b][i][s] * style[b][i])   (transpose)
// v2: write phase packs ushort4 (8 B/lane) instead of scalar u16 (2 B/lane).
__global__ void modx_k(const float* __restrict__ x, const float* __restrict__ style,
                       unsigned short* __restrict__ xmt) {
  __shared__ float tile[32][33];
  int b = blockIdx.z;
  int s0 = blockIdx.x * 32;
  int i0 = blockIdx.y * 32;
  int c = threadIdx.x & 31, r = threadIdx.x >> 5;   // 32 x 8
#pragma unroll
  for (int p = 0; p < 4; ++p) {
    int ii = r + p * 8;
    tile[ii][c] = x[((size_t)(b * INCH + i0 + ii)) * SP + s0 + c] * style[b * INCH + i0 + ii];
  }
  __syncthreads();
  {
    int ss = threadIdx.x >> 3;      // 0..31 s-local
    int c4 = threadIdx.x & 7;       // 0..7 -> 4 i's each
    ushort4 v;
    v.x = f2bf(tile[c4 * 4 + 0][ss]);
    v.y = f2bf(tile[c4 * 4 + 1][ss]);
    v.z = f2bf(tile[c4 * 4 + 2][ss]);
    v.w = f2bf(tile[c4 * 4 + 3][ss]);
    *(ushort4*)&xmt[((size_t)(b * SP + s0 + ss)) * INCH + i0 + c4 * 4] = v;
  }
}

// ---------------- stage 1: T[m, n] = sum_k A[m,k] * B[n,k]
// BM=256 BN=128 BK=64, 512 thr (8 waves 4Mx2N, 64x64/wave), 3-deep LDS ring (3x48KB=144KB).
// Proven zero-conflict BK=64 chunk-XOR swizzle. Tile t+2 staged during tile t; end-of-tile
// wait is COUNTED vmcnt(6) -- drains to 0 only at the tail. 4 phases x 8 MFMA.
// FROZEN from round 3 (110.6 us, MfmaUtil 29, conflicts 0).
__global__ __launch_bounds__(512, 2)
void gemm_k(const unsigned short* __restrict__ A,   // MDIM x INCH
            const unsigned short* __restrict__ Bm,  // NB x SP x INCH
            unsigned short* __restrict__ C) {       // NB x MDIM x SP (bf16)
  __shared__ __align__(16) unsigned short lds[73728];  // 147456 B
  Bm += (size_t)blockIdx.z * SP * INCH;
  C  += (size_t)blockIdx.z * MDIM * SP;
  const int tid  = threadIdx.x;
  const int lane = tid & 63;
  const int wid  = tid >> 6;          // 0..7
  const int wm   = (wid >> 1) * 64;   // m-offset of wave tile
  const int wn   = (wid & 1) * 64;    // n-offset of wave tile
  const int m0 = blockIdx.y * 256;
  const int n0 = blockIdx.x * 128;
  const int r16  = lane & 15;
  const int quad = lane >> 4;

  const int srow = tid >> 3;
  const int sgch = ((tid & 7) ^ (srow & 7)) * 8;
  const int swb  = wid * 512;

  f32x4 acc[4][4];
#pragma unroll
  for (int i = 0; i < 4; ++i)
#pragma unroll
    for (int j = 0; j < 4; ++j) acc[i][j] = (f32x4){0.f, 0.f, 0.f, 0.f};

#define STAGE_A2(T, IT0) do {                                                       \
    unsigned short* _la = &lds[(((T) % 3) * 16384) + swb];                          \
    const unsigned short* _ga = A + (size_t)(m0 + srow) * INCH + (T) * 64 + sgch;   \
    _Pragma("unroll")                                                               \
    for (int _it = (IT0); _it < (IT0) + 2; ++_it)                                   \
      __builtin_amdgcn_global_load_lds(                                             \
          (const __attribute__((address_space(1))) void*)(_ga + (size_t)_it * 64 * INCH), \
          (__attribute__((address_space(3))) void*)(_la + _it * 4096), 16, 0, 0);   \
  } while (0)

#define STAGE_B1(T, IT) do {                                                        \
    unsigned short* _lb = &lds[49152 + (((T) % 3) * 8192) + swb];                   \
    const unsigned short* _gb = Bm + (size_t)(n0 + (IT) * 64 + srow) * INCH + (T) * 64 + sgch; \
    __builtin_amdgcn_global_load_lds(                                               \
        (const __attribute__((address_space(1))) void*)_gb,                         \
        (__attribute__((address_space(3))) void*)(_lb + (IT) * 4096), 16, 0, 0);    \
  } while (0)

#define READ_A(MH) do {                                                             \
    _Pragma("unroll")                                                               \
    for (int _i = 0; _i < 2; ++_i) {                                                \
      const int _ra = wm + ((MH) * 2 + _i) * 16 + r16;                              \
      af[0][_i] = *(const bf16x8*)&As_[_ra * 64 + (((0 + quad) ^ (_ra & 7)) * 8)];  \
      af[1][_i] = *(const bf16x8*)&As_[_ra * 64 + (((4 + quad) ^ (_ra & 7)) * 8)];  \
    }                                                                               \
  } while (0)

#define READ_B(NH) do {                                                             \
    _Pragma("unroll")                                                               \
    for (int _j = 0; _j < 2; ++_j) {                                                \
      const int _rb = wn + ((NH) * 2 + _j) * 16 + r16;                              \
      bfv[0][_j] = *(const bf16x8*)&Bs_[_rb * 64 + (((0 + quad) ^ (_rb & 7)) * 8)]; \
      bfv[1][_j] = *(const bf16x8*)&Bs_[_rb * 64 + (((4 + quad) ^ (_rb & 7)) * 8)]; \
    }                                                                               \
  } while (0)

#define MFMA_Q(MH, NH) do {                                                         \
    __builtin_amdgcn_s_setprio(1);                                                  \
    _Pragma("unroll")                                                               \
    for (int _kk = 0; _kk < 2; ++_kk)                                               \
    _Pragma("unroll")                                                               \
    for (int _i = 0; _i < 2; ++_i)                                                  \
    _Pragma("unroll")                                                               \
    for (int _j = 0; _j < 2; ++_j)                                                  \
      acc[(MH)*2+_i][(NH)*2+_j] = __builtin_amdgcn_mfma_f32_16x16x32_bf16(          \
          af[_kk][_i], bfv[_kk][_j], acc[(MH)*2+_i][(NH)*2+_j], 0, 0, 0);           \
    __builtin_amdgcn_s_setprio(0);                                                  \
  } while (0)

  STAGE_A2(0, 0); STAGE_A2(0, 2); STAGE_B1(0, 0); STAGE_B1(0, 1);
  STAGE_A2(1, 0); STAGE_A2(1, 2); STAGE_B1(1, 0); STAGE_B1(1, 1);
  asm volatile("s_waitcnt vmcnt(6)" ::: "memory");
  __builtin_amdgcn_sched_barrier(0);
  __builtin_amdgcn_s_barrier();

  for (int t = 0; t < 8; ++t) {
    const unsigned short* As_ = &lds[(t % 3) * 16384];
    const unsigned short* Bs_ = &lds[49152 + (t % 3) * 8192];
    const bool st = (t < 6);
    bf16x8 af[2][2], bfv[2][2];
    if (st) STAGE_A2(t + 2, 0);
    READ_A(0); READ_B(0);
    __builtin_amdgcn_s_barrier();
    MFMA_Q(0, 0);
    __builtin_amdgcn_s_barrier();
    if (st) STAGE_A2(t + 2, 2);
    READ_B(1);
    __builtin_amdgcn_s_barrier();
    MFMA_Q(0, 1);
    __builtin_amdgcn_s_barrier();
    if (st) STAGE_B1(t + 2, 0);
    READ_A(1);
    __builtin_amdgcn_s_barrier();
    MFMA_Q(1, 1);
    __builtin_amdgcn_s_barrier();
    if (st) STAGE_B1(t + 2, 1);
    READ_B(0);
    __builtin_amdgcn_s_barrier();
    MFMA_Q(1, 0);
    if (t < 6) {
      asm volatile("s_waitcnt vmcnt(6)" ::: "memory");
      __builtin_amdgcn_sched_barrier(0);
    } else if (t == 6) {
      asm volatile("s_waitcnt vmcnt(0)" ::: "memory");
      __builtin_amdgcn_sched_barrier(0);
    }
    __builtin_amdgcn_s_barrier();
  }
#undef STAGE_A2
#undef STAGE_B1
#undef READ_A
#undef READ_B
#undef MFMA_Q

#pragma unroll
  for (int i = 0; i < 4; ++i)
#pragma unroll
    for (int j = 0; j < 4; ++j)
#pragma unroll
      for (int r = 0; r < 4; ++r) {
        int row = wm + i * 16 + quad * 4 + r;
        int col = wn + j * 16 + r16;
        int pc  = (col >> 3) ^ (row & 15);
        lds[row * 128 + pc * 8 + (col & 7)] = f2bf(acc[i][j][r]);
      }
  __syncthreads();
#pragma unroll
  for (int rr = 0; rr < 8; ++rr) {
    int row = rr * 32 + (tid >> 4);
    int c   = tid & 15;
    int pc  = c ^ (row & 15);
    uint4 v = *(const uint4*)&lds[row * 128 + pc * 8];
    *(uint4*)&C[(size_t)(m0 + row) * SP + n0 + c * 8] = v;
  }
}

// ---------------- stage 2: separable parity-combine + 4x4 blur + demod
// v2: STRIP 16 (halo 18/16 vs 10/8), 16B tap loads, 8192 blocks. LDS 50.3KB -> 3 blocks/CU.
#define STRIP 16
#define TLSTR 70
#define TLROWS 18
__global__ __launch_bounds__(256)
void combine_k(const unsigned short* __restrict__ T, const float* __restrict__ dm,
               float* __restrict__ out) {
  __shared__ __align__(16) unsigned short TlB[9 * TLROWS * TLSTR + 4];  // 22688 B
  __shared__ __align__(16) float V[3 * TLROWS * 128];                   // 27648 B
  T   += (size_t)blockIdx.z * MDIM * SP;
  dm  += (size_t)blockIdx.z * OUTCH;
  out += (size_t)blockIdx.z * OUTCH * 128 * 128;
  const int o  = blockIdx.y;
  const int Y0 = blockIdx.x * STRIP;
  const int tid = threadIdx.x;

  // zero-fill TlB (halo rows/cols must read 0)
  {
    uint4* tz = (uint4*)TlB;
    for (int idx = tid; idx < (9 * TLROWS * TLSTR + 4) / 8; idx += 256)   // 1418
      tz[idx] = (uint4){0u, 0u, 0u, 0u};
  }
  __syncthreads();

  // tap load: 9 taps x 18 rows x 8 chunks of 8 cols (16B global loads); 1296 tasks
  for (int idx = tid; idx < 9 * TLROWS * 8; idx += 256) {
    int tap = idx / (TLROWS * 8);
    int rem = idx - tap * (TLROWS * 8);
    int ry  = rem >> 3;
    int c8  = rem & 7;
    int Yg  = Y0 - 1 + ry;
    if ((unsigned)Yg < 64u) {
      const unsigned short* src = T + (size_t)(tap * OUTCH + o) * SP + Yg * 64 + c8 * 8;
      ushort4 a  = *(const ushort4*)(src);
      ushort4 b4 = *(const ushort4*)(src + 4);
      unsigned short* dst = &TlB[(tap * TLROWS + ry) * TLSTR + 4 + c8 * 8];
      *(ushort2*)(dst)     = make_ushort2(a.x, a.y);
      *(ushort2*)(dst + 2) = make_ushort2(a.z, a.w);
      *(ushort2*)(dst + 4) = make_ushort2(b4.x, b4.y);
      *(ushort2*)(dst + 6) = make_ushort2(b4.z, b4.w);
    }
  }
  __syncthreads();

  // x-pass: 54 row-tasks (c 0..2, yr 0..17) x 8 x-chunks of 8 -> V ; 432 tasks
  for (int idx = tid; idx < 3 * TLROWS * 8; idx += 256) {
    const int r  = idx >> 3;
    const int xc = idx & 7;
    const int c  = r / TLROWS;
    const int yr = r - c * TLROWS;
    const int X0 = xc * 8;
    float td[3][12];
#pragma unroll
    for (int d = 0; d < 3; ++d) {
      const unsigned short* src = &TlB[((c * 3 + d) * TLROWS + yr) * TLSTR + 2 + X0];
#pragma unroll
      for (int k = 0; k < 6; ++k) {
        ushort2 u2 = *(const ushort2*)(src + 2 * k);
        td[d][2 * k]     = bf2f(u2.x);
        td[d][2 * k + 1] = bf2f(u2.y);
      }
    }
    float vout[16];
#pragma unroll
    for (int Xl = 0; Xl < 8; ++Xl) {
      float a0 = td[0][Xl + 1], a1 = td[0][Xl + 2], a2 = td[0][Xl + 3];
      float b0 = td[1][Xl + 1], b1 = td[1][Xl + 2], b2 = td[1][Xl + 3];
      float c0 = td[2][Xl + 1], c1 = td[2][Xl + 2], c2 = td[2][Xl + 3];
      vout[2 * Xl]     = b0 + 3.f * c0 + 3.f * a1 + 3.f * b1 + c1 + a2;
      vout[2 * Xl + 1] = c0 + a1 + 3.f * b1 + 3.f * c1 + 3.f * a2 + b2;
    }
    float* vr = &V[(c * TLROWS + yr) * 128];
#pragma unroll
    for (int j = 0; j < 4; ++j) {
      int l = 4 * xc + j;
      int p = (l & ~3) | ((l & 3) ^ ((l >> 3) & 3));
      *(f32x4*)(vr + p * 4) = (f32x4){vout[4 * j], vout[4 * j + 1], vout[4 * j + 2], vout[4 * j + 3]};
    }
  }
  __syncthreads();

  // y-pass: 32 out rows x 32 chunks; thread = (y=tid>>3, chunk tid&7 + 8*xg)
  {
    const int y  = tid >> 3;        // 0..31
    const int py = y & 1;
    const int Yl = y >> 1;          // 0..15
    const float dmv = dm[o] * (1.0f / 16.0f);
    float* orow = out + ((size_t)o * 128 + (Y0 * 2 + y)) * 128;
#pragma unroll
    for (int xg = 0; xg < 4; ++xg) {
      int l = (tid & 7) + 8 * xg;
      int p = (l & ~3) | ((l & 3) ^ ((l >> 3) & 3));
      int off = p * 4;
      f32x4 v01 = *(const f32x4*)&V[((0 * TLROWS) + Yl + 1) * 128 + off];
      f32x4 v02 = *(const f32x4*)&V[((0 * TLROWS) + Yl + 2) * 128 + off];
      f32x4 v10 = *(const f32x4*)&V[((1 * TLROWS) + Yl + 0) * 128 + off];
      f32x4 v11 = *(const f32x4*)&V[((1 * TLROWS) + Yl + 1) * 128 + off];
      f32x4 v12 = *(const f32x4*)&V[((1 * TLROWS) + Yl + 2) * 128 + off];
      f32x4 v20 = *(const f32x4*)&V[((2 * TLROWS) + Yl + 0) * 128 + off];
      f32x4 v21 = *(const f32x4*)&V[((2 * TLROWS) + Yl + 1) * 128 + off];
      f32x4 v22 = *(const f32x4*)&V[((2 * TLROWS) + Yl + 2) * 128 + off];
      f32x4 r;
      if (py == 0)
        r = v10 + 3.f * v20 + 3.f * v01 + 3.f * v11 + v21 + v02;
      else
        r = v20 + v01 + 3.f * v11 + 3.f * v21 + 3.f * v02 + v12;
      r *= dmv;
      *(f32x4*)(orow + l * 4) = r;
    }
  }
}

extern "C" void kernel_launch(void* const* d_in, const int* in_sizes, int n_in,
                              void* d_out, int out_size, void* d_ws, size_t ws_size,
                              hipStream_t stream) {
  const float* x    = (const float*)d_in[0];
  const float* w    = (const float*)d_in[1];
  const float* aff  = (const float*)d_in[2];
  const float* bias = (const float*)d_in[3];
  const float* cw   = (const float*)d_in[4];
  float* out = (float*)d_out;
  char* ws = (char*)d_ws;
  // ws layout: style 16K | S 512K | demod 8K | w9 2.25M | xmt 32M | T(bf16) 151M
  float* style        = (float*)(ws);
  float* S            = (float*)(ws + 16384);
  float* dmod         = (float*)(ws + 540672);
  unsigned short* w9  = (unsigned short*)(ws + 548864);
  unsigned short* xmt = (unsigned short*)(ws + 2908160);
  unsigned short* T   = (unsigned short*)(ws + 36462592);

  hipLaunchKernelGGL(prep_k, dim3(528), dim3(256), 0, stream, w, aff, bias, style, cw, S, w9);
  hipLaunchKernelGGL(demod_k, dim3(128), dim3(256), 0, stream, style, S, dmod);
  hipLaunchKernelGGL(modx_k, dim3(128, 16, 8), dim3(256), 0, stream, x, style, xmt);
  hipLaunchKernelGGL(gemm_k, dim3(32, 9, NB), dim3(512), 0, stream, w9, xmt, T);
  hipLaunchKernelGGL(combine_k, dim3(64 / STRIP, 256, NB), dim3(256), 0, stream, T, dmod, out);
}

// Round 5
// 370.982 us; speedup vs baseline: 1.1124x; 1.0383x over previous
//
#include <hip/hip_runtime.h>
#include <hip/hip_bf16.h>
#include <math.h>

#define NB 8
#define INCH 512
#define OUTCH 256
#define SP 4096          // 64*64 spatial
#define LAT 512
#define NTAP 9
#define MDIM (NTAP*OUTCH)   // 2304

#define INV_SQRT_LAT 0.044194173824159216f   // 1/sqrt(512)
#define WSCALE 0.014731391274719738f         // 1/sqrt(512*9)

typedef __bf16 bf16x8 __attribute__((ext_vector_type(8)));
typedef float  f32x4  __attribute__((ext_vector_type(4)));

__device__ __forceinline__ unsigned short f2bf(float f) {
  unsigned u = __float_as_uint(f);
  u += 0x7fffu + ((u >> 16) & 1u);       // round-to-nearest-even
  return (unsigned short)(u >> 16);
}
__device__ __forceinline__ float bf2f(unsigned short v) {
  return __uint_as_float((unsigned)v << 16);
}

// ---------------- stage 0a+0b fused: style GEMV (blocks 0..15) + weight prep (blocks 16..527)
__global__ void prep_k(const float* __restrict__ w, const float* __restrict__ aff,
                       const float* __restrict__ bias, float* __restrict__ style,
                       const float* __restrict__ cw, float* __restrict__ S,
                       unsigned short* __restrict__ w9) {
  if (blockIdx.x < 16) {
    int gid = blockIdx.x * 256 + threadIdx.x;       // 4096
    int b = gid >> 9, i = gid & 511;
    const float4* wv = (const float4*)(w + (size_t)b * LAT);
    const float4* av = (const float4*)(aff + (size_t)i * LAT);
    float s = 0.f;
#pragma unroll 4
    for (int l = 0; l < LAT / 4; ++l) {
      float4 a = av[l], ww = wv[l];
      s += a.x * ww.x + a.y * ww.y + a.z * ww.z + a.w * ww.w;
    }
    style[gid] = s * INV_SQRT_LAT + bias[i];
  } else {
    int gid = (blockIdx.x - 16) * 256 + threadIdx.x;  // 131072 = 256*512
    int o = gid >> 9, i = gid & 511;
    const float* p = cw + (size_t)gid * 9;            // layout (o,i,3,3)
    float ss = 0.f, v[9];
#pragma unroll
    for (int t = 0; t < 9; ++t) { v[t] = p[t]; ss += v[t] * v[t]; }
    S[gid] = ss * (WSCALE * WSCALE);
#pragma unroll
    for (int t = 0; t < 9; ++t)
      w9[((size_t)(t * OUTCH + o)) * INCH + i] = f2bf(v[t] * WSCALE);
  }
}

// ---------------- stage 0c: demod[b,o] = rsqrt(sum_i style^2 * S + 1e-8)
// v2: 16 threads per output, 128 blocks.
__global__ void demod_k(const float* __restrict__ style, const float* __restrict__ S,
                        float* __restrict__ dmod) {
  int g = blockIdx.x * 16 + (threadIdx.x >> 4);    // 2048 outputs
  int j = threadIdx.x & 15;
  int b = g >> 8, o = g & 255;
  const float4* sv = (const float4*)(style + (size_t)b * INCH + j * 32);
  const float4* Sv = (const float4*)(S + (size_t)o * INCH + j * 32);
  float acc = 0.f;
#pragma unroll
  for (int l = 0; l < 8; ++l) {
    float4 st = sv[l], s2 = Sv[l];
    acc += st.x * st.x * s2.x + st.y * st.y * s2.y + st.z * st.z * s2.z + st.w * st.w * s2.w;
  }
#pragma unroll
  for (int d = 1; d < 16; d <<= 1) acc += __shfl_xor(acc, d, 16);
  if (j == 0) dmod[g] = 1.0f / sqrtf(acc + 1e-8f);
}

// ---------------- stage 0d: xmt[b][s][i] = bf16(x[b][i][s] * style[b][i])   (transpose)
// v2: write phase packs ushort4 (8 B/lane).
__global__ void modx_k(const float* __restrict__ x, const float* __restrict__ style,
                       unsigned short* __restrict__ xmt) {
  __shared__ float tile[32][33];
  int b = blockIdx.z;
  int s0 = blockIdx.x * 32;
  int i0 = blockIdx.y * 32;
  int c = threadIdx.x & 31, r = threadIdx.x >> 5;   // 32 x 8
#pragma unroll
  for (int p = 0; p < 4; ++p) {
    int ii = r + p * 8;
    tile[ii][c] = x[((size_t)(b * INCH + i0 + ii)) * SP + s0 + c] * style[b * INCH + i0 + ii];
  }
  __syncthreads();
  {
    int ss = threadIdx.x >> 3;      // 0..31 s-local
    int c4 = threadIdx.x & 7;       // 0..7 -> 4 i's each
    ushort4 v;
    v.x = f2bf(tile[c4 * 4 + 0][ss]);
    v.y = f2bf(tile[c4 * 4 + 1][ss]);
    v.z = f2bf(tile[c4 * 4 + 2][ss]);
    v.w = f2bf(tile[c4 * 4 + 3][ss]);
    *(ushort4*)&xmt[((size_t)(b * SP + s0 + ss)) * INCH + i0 + c4 * 4] = v;
  }
}

// ---------------- stage 1: T[m, n] = sum_k A[m,k] * B[n,k]
// BM=256 BN=128 BK=64, 512 thr (8 waves 4Mx2N, 64x64/wave), 3-deep LDS ring (144KB).
// v4: ONE barrier per K-tile (was 8). Ring-3 makes intra-tile barriers unnecessary:
// stages for t+2 write slot (t+2)%3 == (t-1)%3 whose reads finished before tile t's
// opening barrier; tile t+1 residency guaranteed by the counted vmcnt(6)+barrier at
// tile end. Body = 6 stages + 16 ds_read_b128 (all frags live, no B re-read) + 32 MFMA;
// compiler does the fine lgkmcnt interleave. Zero-conflict BK=64 chunk-XOR swizzle kept.
__global__ __launch_bounds__(512, 2)
void gemm_k(const unsigned short* __restrict__ A,   // MDIM x INCH
            const unsigned short* __restrict__ Bm,  // NB x SP x INCH
            unsigned short* __restrict__ C) {       // NB x MDIM x SP (bf16)
  __shared__ __align__(16) unsigned short lds[73728];  // 147456 B
  Bm += (size_t)blockIdx.z * SP * INCH;
  C  += (size_t)blockIdx.z * MDIM * SP;
  const int tid  = threadIdx.x;
  const int lane = tid & 63;
  const int wid  = tid >> 6;          // 0..7
  const int wm   = (wid >> 1) * 64;   // m-offset of wave tile
  const int wn   = (wid & 1) * 64;    // n-offset of wave tile
  const int m0 = blockIdx.y * 256;
  const int n0 = blockIdx.x * 128;
  const int r16  = lane & 15;
  const int quad = lane >> 4;

  const int srow = tid >> 3;
  const int sgch = ((tid & 7) ^ (srow & 7)) * 8;
  const int swb  = wid * 512;

  f32x4 acc[4][4];
#pragma unroll
  for (int i = 0; i < 4; ++i)
#pragma unroll
    for (int j = 0; j < 4; ++j) acc[i][j] = (f32x4){0.f, 0.f, 0.f, 0.f};

#define STAGE_A2(T, IT0) do {                                                       \
    unsigned short* _la = &lds[(((T) % 3) * 16384) + swb];                          \
    const unsigned short* _ga = A + (size_t)(m0 + srow) * INCH + (T) * 64 + sgch;   \
    _Pragma("unroll")                                                               \
    for (int _it = (IT0); _it < (IT0) + 2; ++_it)                                   \
      __builtin_amdgcn_global_load_lds(                                             \
          (const __attribute__((address_space(1))) void*)(_ga + (size_t)_it * 64 * INCH), \
          (__attribute__((address_space(3))) void*)(_la + _it * 4096), 16, 0, 0);   \
  } while (0)

#define STAGE_B1(T, IT) do {                                                        \
    unsigned short* _lb = &lds[49152 + (((T) % 3) * 8192) + swb];                   \
    const unsigned short* _gb = Bm + (size_t)(n0 + (IT) * 64 + srow) * INCH + (T) * 64 + sgch; \
    __builtin_amdgcn_global_load_lds(                                               \
        (const __attribute__((address_space(1))) void*)_gb,                         \
        (__attribute__((address_space(3))) void*)(_lb + (IT) * 4096), 16, 0, 0);    \
  } while (0)

  // prologue: stage tiles 0 and 1 (12 loads/wave); counted wait for tile 0 only.
  STAGE_A2(0, 0); STAGE_A2(0, 2); STAGE_B1(0, 0); STAGE_B1(0, 1);
  STAGE_A2(1, 0); STAGE_A2(1, 2); STAGE_B1(1, 0); STAGE_B1(1, 1);
  asm volatile("s_waitcnt vmcnt(6)" ::: "memory");
  __builtin_amdgcn_sched_barrier(0);
  __builtin_amdgcn_s_barrier();

  for (int t = 0; t < 8; ++t) {
    const unsigned short* As_ = &lds[(t % 3) * 16384];
    const unsigned short* Bs_ = &lds[49152 + (t % 3) * 8192];
    // stage tile t+2 (slot (t+2)%3 == (t-1)%3, reads of which ended pre-barrier)
    if (t < 6) {
      STAGE_A2(t + 2, 0); STAGE_A2(t + 2, 2);
      STAGE_B1(t + 2, 0); STAGE_B1(t + 2, 1);
    }
    // read all fragments for tile t: A 4 frags x 2kk, B 4 frags x 2kk (16 b128)
    bf16x8 af[2][4], bfv[2][4];
#pragma unroll
    for (int i = 0; i < 4; ++i) {
      const int ra = wm + i * 16 + r16;
      af[0][i] = *(const bf16x8*)&As_[ra * 64 + (((0 + quad) ^ (ra & 7)) * 8)];
      af[1][i] = *(const bf16x8*)&As_[ra * 64 + (((4 + quad) ^ (ra & 7)) * 8)];
    }
#pragma unroll
    for (int j = 0; j < 4; ++j) {
      const int rb = wn + j * 16 + r16;
      bfv[0][j] = *(const bf16x8*)&Bs_[rb * 64 + (((0 + quad) ^ (rb & 7)) * 8)];
      bfv[1][j] = *(const bf16x8*)&Bs_[rb * 64 + (((4 + quad) ^ (rb & 7)) * 8)];
    }
    __builtin_amdgcn_s_setprio(1);
#pragma unroll
    for (int kk = 0; kk < 2; ++kk)
#pragma unroll
      for (int i = 0; i < 4; ++i)
#pragma unroll
        for (int j = 0; j < 4; ++j)
          acc[i][j] = __builtin_amdgcn_mfma_f32_16x16x32_bf16(
              af[kk][i], bfv[kk][j], acc[i][j], 0, 0, 0);
    __builtin_amdgcn_s_setprio(0);
    // end-of-tile: tile t+1 must be resident; keep tile t+2 in flight (counted).
    if (t < 6) {
      asm volatile("s_waitcnt vmcnt(6)" ::: "memory");
      __builtin_amdgcn_sched_barrier(0);
    } else if (t == 6) {
      asm volatile("s_waitcnt vmcnt(0)" ::: "memory");
      __builtin_amdgcn_sched_barrier(0);
    }
    __builtin_amdgcn_s_barrier();
  }
#undef STAGE_A2
#undef STAGE_B1

  // epilogue: restage 256x128 bf16 tile in LDS (16-chunk XOR swizzle per 256B row), store x4.
  // C/D layout col=lane&15, row=quad*4+reg [m89].
#pragma unroll
  for (int i = 0; i < 4; ++i)
#pragma unroll
    for (int j = 0; j < 4; ++j)
#pragma unroll
      for (int r = 0; r < 4; ++r) {
        int row = wm + i * 16 + quad * 4 + r;
        int col = wn + j * 16 + r16;
        int pc  = (col >> 3) ^ (row & 15);
        lds[row * 128 + pc * 8 + (col & 7)] = f2bf(acc[i][j][r]);
      }
  __syncthreads();
#pragma unroll
  for (int rr = 0; rr < 8; ++rr) {
    int row = rr * 32 + (tid >> 4);
    int c   = tid & 15;
    int pc  = c ^ (row & 15);
    uint4 v = *(const uint4*)&lds[row * 128 + pc * 8];
    *(uint4*)&C[(size_t)(m0 + row) * SP + n0 + c * 8] = v;
  }
}

// ---------------- stage 2: separable parity-combine + 4x4 blur + demod
// v2: STRIP 16 (halo 18/16), 16B tap loads, 8192 blocks. LDS 50.3KB -> 3 blocks/CU.
#define STRIP 16
#define TLSTR 70
#define TLROWS 18
__global__ __launch_bounds__(256)
void combine_k(const unsigned short* __restrict__ T, const float* __restrict__ dm,
               float* __restrict__ out) {
  __shared__ __align__(16) unsigned short TlB[9 * TLROWS * TLSTR + 4];  // 22688 B
  __shared__ __align__(16) float V[3 * TLROWS * 128];                   // 27648 B
  T   += (size_t)blockIdx.z * MDIM * SP;
  dm  += (size_t)blockIdx.z * OUTCH;
  out += (size_t)blockIdx.z * OUTCH * 128 * 128;
  const int o  = blockIdx.y;
  const int Y0 = blockIdx.x * STRIP;
  const int tid = threadIdx.x;

  // zero-fill TlB (halo rows/cols must read 0)
  {
    uint4* tz = (uint4*)TlB;
    for (int idx = tid; idx < (9 * TLROWS * TLSTR + 4) / 8; idx += 256)   // 1418
      tz[idx] = (uint4){0u, 0u, 0u, 0u};
  }
  __syncthreads();

  // tap load: 9 taps x 18 rows x 8 chunks of 8 cols (16B global loads); 1296 tasks
  for (int idx = tid; idx < 9 * TLROWS * 8; idx += 256) {
    int tap = idx / (TLROWS * 8);
    int rem = idx - tap * (TLROWS * 8);
    int ry  = rem >> 3;
    int c8  = rem & 7;
    int Yg  = Y0 - 1 + ry;
    if ((unsigned)Yg < 64u) {
      const unsigned short* src = T + (size_t)(tap * OUTCH + o) * SP + Yg * 64 + c8 * 8;
      ushort4 a  = *(const ushort4*)(src);
      ushort4 b4 = *(const ushort4*)(src + 4);
      unsigned short* dst = &TlB[(tap * TLROWS + ry) * TLSTR + 4 + c8 * 8];
      *(ushort2*)(dst)     = make_ushort2(a.x, a.y);
      *(ushort2*)(dst + 2) = make_ushort2(a.z, a.w);
      *(ushort2*)(dst + 4) = make_ushort2(b4.x, b4.y);
      *(ushort2*)(dst + 6) = make_ushort2(b4.z, b4.w);
    }
  }
  __syncthreads();

  // x-pass: 54 row-tasks (c 0..2, yr 0..17) x 8 x-chunks of 8 -> V ; 432 tasks
  for (int idx = tid; idx < 3 * TLROWS * 8; idx += 256) {
    const int r  = idx >> 3;
    const int xc = idx & 7;
    const int c  = r / TLROWS;
    const int yr = r - c * TLROWS;
    const int X0 = xc * 8;
    float td[3][12];
#pragma unroll
    for (int d = 0; d < 3; ++d) {
      const unsigned short* src = &TlB[((c * 3 + d) * TLROWS + yr) * TLSTR + 2 + X0];
#pragma unroll
      for (int k = 0; k < 6; ++k) {
        ushort2 u2 = *(const ushort2*)(src + 2 * k);
        td[d][2 * k]     = bf2f(u2.x);
        td[d][2 * k + 1] = bf2f(u2.y);
      }
    }
    float vout[16];
#pragma unroll
    for (int Xl = 0; Xl < 8; ++Xl) {
      float a0 = td[0][Xl + 1], a1 = td[0][Xl + 2], a2 = td[0][Xl + 3];
      float b0 = td[1][Xl + 1], b1 = td[1][Xl + 2], b2 = td[1][Xl + 3];
      float c0 = td[2][Xl + 1], c1 = td[2][Xl + 2], c2 = td[2][Xl + 3];
      vout[2 * Xl]     = b0 + 3.f * c0 + 3.f * a1 + 3.f * b1 + c1 + a2;
      vout[2 * Xl + 1] = c0 + a1 + 3.f * b1 + 3.f * c1 + 3.f * a2 + b2;
    }
    float* vr = &V[(c * TLROWS + yr) * 128];
#pragma unroll
    for (int j = 0; j < 4; ++j) {
      int l = 4 * xc + j;
      int p = (l & ~3) | ((l & 3) ^ ((l >> 3) & 3));
      *(f32x4*)(vr + p * 4) = (f32x4){vout[4 * j], vout[4 * j + 1], vout[4 * j + 2], vout[4 * j + 3]};
    }
  }
  __syncthreads();

  // y-pass: 32 out rows x 32 chunks; thread = (y=tid>>3, chunk tid&7 + 8*xg)
  {
    const int y  = tid >> 3;        // 0..31
    const int py = y & 1;
    const int Yl = y >> 1;          // 0..15
    const float dmv = dm[o] * (1.0f / 16.0f);
    float* orow = out + ((size_t)o * 128 + (Y0 * 2 + y)) * 128;
#pragma unroll
    for (int xg = 0; xg < 4; ++xg) {
      int l = (tid & 7) + 8 * xg;
      int p = (l & ~3) | ((l & 3) ^ ((l >> 3) & 3));
      int off = p * 4;
      f32x4 v01 = *(const f32x4*)&V[((0 * TLROWS) + Yl + 1) * 128 + off];
      f32x4 v02 = *(const f32x4*)&V[((0 * TLROWS) + Yl + 2) * 128 + off];
      f32x4 v10 = *(const f32x4*)&V[((1 * TLROWS) + Yl + 0) * 128 + off];
      f32x4 v11 = *(const f32x4*)&V[((1 * TLROWS) + Yl + 1) * 128 + off];
      f32x4 v12 = *(const f32x4*)&V[((1 * TLROWS) + Yl + 2) * 128 + off];
      f32x4 v20 = *(const f32x4*)&V[((2 * TLROWS) + Yl + 0) * 128 + off];
      f32x4 v21 = *(const f32x4*)&V[((2 * TLROWS) + Yl + 1) * 128 + off];
      f32x4 v22 = *(const f32x4*)&V[((2 * TLROWS) + Yl + 2) * 128 + off];
      f32x4 r;
      if (py == 0)
        r = v10 + 3.f * v20 + 3.f * v01 + 3.f * v11 + v21 + v02;
      else
        r = v20 + v01 + 3.f * v11 + 3.f * v21 + 3.f * v02 + v12;
      r *= dmv;
      *(f32x4*)(orow + l * 4) = r;
    }
  }
}

extern "C" void kernel_launch(void* const* d_in, const int* in_sizes, int n_in,
                              void* d_out, int out_size, void* d_ws, size_t ws_size,
                              hipStream_t stream) {
  const float* x    = (const float*)d_in[0];
  const float* w    = (const float*)d_in[1];
  const float* aff  = (const float*)d_in[2];
  const float* bias = (const float*)d_in[3];
  const float* cw   = (const float*)d_in[4];
  float* out = (float*)d_out;
  char* ws = (char*)d_ws;
  // ws layout: style 16K | S 512K | demod 8K | w9 2.25M | xmt 32M | T(bf16) 151M
  float* style        = (float*)(ws);
  float* S            = (float*)(ws + 16384);
  float* dmod         = (float*)(ws + 540672);
  unsigned short* w9  = (unsigned short*)(ws + 548864);
  unsigned short* xmt = (unsigned short*)(ws + 2908160);
  unsigned short* T   = (unsigned short*)(ws + 36462592);

  hipLaunchKernelGGL(prep_k, dim3(528), dim3(256), 0, stream, w, aff, bias, style, cw, S, w9);
  hipLaunchKernelGGL(demod_k, dim3(128), dim3(256), 0, stream, style, S, dmod);
  hipLaunchKernelGGL(modx_k, dim3(128, 16, 8), dim3(256), 0, stream, x, style, xmt);
  hipLaunchKernelGGL(gemm_k, dim3(32, 9, NB), dim3(512), 0, stream, w9, xmt, T);
  hipLaunchKernelGGL(combine_k, dim3(64 / STRIP, 256, NB), dim3(256), 0, stream, T, dmod, out);
}